// Round 1
// baseline (6160.352 us; speedup 1.0000x reference)
//
#include <hip/hip_runtime.h>
#include <math.h>

#define BDIM 4
#define SDIM 2048
#define EDIM 768
#define HDIM 12
#define DDIM 64
#define MROWS (BDIM * SDIM)  // 8192

// C[M,N] = A[M,K] * W[K,N] + bias[N].  64x64 tile, BK=16, 256 threads, 4x4/thread.
__global__ __launch_bounds__(256) void gemm_bias_64(
    const float* __restrict__ A, const float* __restrict__ Wm,
    const float* __restrict__ bias, float* __restrict__ C,
    int Mdim, int Ndim, int Kdim) {
  __shared__ float As[64][17];  // [m][k], +1 pad
  __shared__ float Bs[16][65];  // [k][n], +1 pad
  const int tid = threadIdx.x;
  const int tx = tid & 15, ty = tid >> 4;
  const int bm = blockIdx.y * 64, bn = blockIdx.x * 64;
  float acc[4][4] = {};
  for (int k0 = 0; k0 < Kdim; k0 += 16) {
    // A tile: 64 rows x 16 cols (1024 elems, 4/thread)
    for (int i = 0; i < 4; ++i) {
      int idx = i * 256 + tid;
      int r = idx >> 4, c = idx & 15;
      As[r][c] = A[(size_t)(bm + r) * Kdim + k0 + c];
    }
    // W tile: 16 rows x 64 cols
    for (int i = 0; i < 4; ++i) {
      int idx = i * 256 + tid;
      int r = idx >> 6, c = idx & 63;
      Bs[r][c] = Wm[(size_t)(k0 + r) * Ndim + bn + c];
    }
    __syncthreads();
#pragma unroll
    for (int kk = 0; kk < 16; ++kk) {
      float a[4], b[4];
#pragma unroll
      for (int i = 0; i < 4; ++i) a[i] = As[ty * 4 + i][kk];
#pragma unroll
      for (int j = 0; j < 4; ++j) b[j] = Bs[kk][tx * 4 + j];
#pragma unroll
      for (int i = 0; i < 4; ++i)
#pragma unroll
        for (int j = 0; j < 4; ++j) acc[i][j] += a[i] * b[j];
    }
    __syncthreads();
  }
#pragma unroll
  for (int i = 0; i < 4; ++i)
#pragma unroll
    for (int j = 0; j < 4; ++j) {
      int r = bm + ty * 4 + i, c = bn + tx * 4 + j;
      C[(size_t)r * Ndim + c] = acc[i][j] + bias[c];
    }
}

// Flash-style causal attention. qkv layout [B, S, 3, H, D]; out [B, S, E].
// One block per (q-tile of 64 rows, b*h). 256 threads: thread t handles
// row r = t>>2, dim quarter qd = t&3 (16 dims).
__global__ __launch_bounds__(256) void attn_kernel(
    const float* __restrict__ qkv, float* __restrict__ attn) {
  __shared__ float Qs[64][65];
  __shared__ float Ks[64][65];
  __shared__ float Vs[64][65];
  __shared__ float Ss[64][65];
  const int bh = blockIdx.y;
  const int b = bh / HDIM, h = bh % HDIM;
  const int qt = blockIdx.x;
  const int tid = threadIdx.x;
  const int r = tid >> 2;
  const int qd = tid & 3;
  const float scale = 0.125f;  // 1/sqrt(64)

  // Load Q tile (coalesced: consecutive tid -> consecutive col)
  for (int i = 0; i < 16; ++i) {
    int idx = i * 256 + tid;
    int rr = idx >> 6, cc = idx & 63;
    Qs[rr][cc] =
        qkv[((size_t)(b * SDIM + qt * 64 + rr) * 3 + 0) * EDIM + h * DDIM + cc];
  }

  float o[16];
#pragma unroll
  for (int e = 0; e < 16; ++e) o[e] = 0.f;
  float m = -1e30f, l = 0.f;

  for (int kt = 0; kt <= qt; ++kt) {
    __syncthreads();
    for (int i = 0; i < 16; ++i) {
      int idx = i * 256 + tid;
      int rr = idx >> 6, cc = idx & 63;
      size_t row = (size_t)(b * SDIM + kt * 64 + rr) * 3;
      Ks[rr][cc] = qkv[(row + 1) * EDIM + h * DDIM + cc];
      Vs[rr][cc] = qkv[(row + 2) * EDIM + h * DDIM + cc];
    }
    __syncthreads();
    // Scores: row r, cols qd*16 .. qd*16+15
#pragma unroll
    for (int j = 0; j < 16; ++j) {
      int c = qd * 16 + j;
      float s = 0.f;
#pragma unroll
      for (int d = 0; d < 64; ++d) s += Qs[r][d] * Ks[c][d];
      s *= scale;
      if (kt == qt && c > r) s = -1e30f;
      Ss[r][c] = s;
    }
    __syncthreads();
    // Online softmax update (each of 4 threads/row does it redundantly)
    float mt = -1e30f;
    for (int c = 0; c < 64; ++c) mt = fmaxf(mt, Ss[r][c]);
    float newm = fmaxf(m, mt);
    float alpha = __expf(m - newm);
    l *= alpha;
#pragma unroll
    for (int e = 0; e < 16; ++e) o[e] *= alpha;
    for (int c = 0; c < 64; ++c) {
      float p = __expf(Ss[r][c] - newm);
      l += p;
#pragma unroll
      for (int e = 0; e < 16; ++e) o[e] += p * Vs[c][qd * 16 + e];
    }
    m = newm;
    __syncthreads();
  }
  float inv = 1.f / l;
#pragma unroll
  for (int e = 0; e < 16; ++e)
    attn[(size_t)(b * SDIM + qt * 64 + r) * EDIM + h * DDIM + qd * 16 + e] =
        o[e] * inv;
}

extern "C" void kernel_launch(void* const* d_in, const int* in_sizes, int n_in,
                              void* d_out, int out_size, void* d_ws,
                              size_t ws_size, hipStream_t stream) {
  const float* x = (const float*)d_in[0];
  const float* w_qkv = (const float*)d_in[1];
  const float* b_qkv = (const float*)d_in[2];
  const float* w_proj = (const float*)d_in[3];
  const float* b_proj = (const float*)d_in[4];
  float* out = (float*)d_out;

  float* qkv = (float*)d_ws;                          // [8192, 2304]
  float* attn = qkv + (size_t)MROWS * 3 * EDIM;       // [8192, 768]

  dim3 blk(256);
  // QKV projection: [8192,768] x [768,2304]
  gemm_bias_64<<<dim3(3 * EDIM / 64, MROWS / 64), blk, 0, stream>>>(
      x, w_qkv, b_qkv, qkv, MROWS, 3 * EDIM, EDIM);
  // Causal attention
  attn_kernel<<<dim3(SDIM / 64, BDIM * HDIM), blk, 0, stream>>>(qkv, attn);
  // Output projection: [8192,768] x [768,768]
  gemm_bias_64<<<dim3(EDIM / 64, MROWS / 64), blk, 0, stream>>>(
      attn, w_proj, b_proj, out, MROWS, EDIM, EDIM);
}

// Round 2
// 318.369 us; speedup vs baseline: 19.3497x; 19.3497x over previous
//
#include <hip/hip_runtime.h>

#define SDIM 2048
#define EDIM 768
#define HDIM 12
#define DDIM 64
#define BDIM 4
#define MROWS (BDIM * SDIM)   // 8192
#define NQKV (3 * EDIM)       // 2304
#define NBH (BDIM * HDIM)     // 48

typedef __attribute__((ext_vector_type(8))) short s16x8;   // 8 bf16
typedef __attribute__((ext_vector_type(4))) float f32x4;

__device__ __forceinline__ short f2b(float x) {
  union { float f; unsigned u; } v; v.f = x;
  unsigned r = v.u + 0x7fffu + ((v.u >> 16) & 1u);
  return (short)(r >> 16);
}

// ---------------- elementwise fp32 -> bf16 ----------------
__global__ __launch_bounds__(256) void convert_bf16(
    const float* __restrict__ in, short* __restrict__ out, int n4) {
  int i = blockIdx.x * 256 + threadIdx.x;
  int stride = gridDim.x * 256;
  for (; i < n4; i += stride) {
    float4 v = ((const float4*)in)[i];
    short4 o;
    o.x = f2b(v.x); o.y = f2b(v.y); o.z = f2b(v.z); o.w = f2b(v.w);
    ((short4*)out)[i] = o;
  }
}

// ---------------- transpose + convert: [K][N] f32 -> [N][K] bf16 ----------------
__global__ __launch_bounds__(256) void transpose_bf16(
    const float* __restrict__ in, short* __restrict__ out, int K, int N) {
  __shared__ float t[32][33];
  int n0 = blockIdx.x * 32, k0 = blockIdx.y * 32;
  int tx = threadIdx.x & 31, ty = threadIdx.x >> 5;  // ty 0..7
#pragma unroll
  for (int i = 0; i < 4; ++i)
    t[ty + 8 * i][tx] = in[(size_t)(k0 + ty + 8 * i) * N + n0 + tx];
  __syncthreads();
#pragma unroll
  for (int i = 0; i < 4; ++i)
    out[(size_t)(n0 + ty + 8 * i) * K + k0 + tx] = f2b(t[tx][ty + 8 * i]);
}

// ---------------- bf16 MFMA GEMM, 128x128 tile, BK=32, 4 waves ----------------
// A [M][K] bf16, Bt [N][K] bf16. mode 0: scatter to q/k/v bf16 (+bias);
// mode 1: fp32 out (+bias).
__global__ __launch_bounds__(256) void gemm_bf16(
    const short* __restrict__ A, const short* __restrict__ Bt,
    const float* __restrict__ bias, int M, int N, int K, int mode,
    short* __restrict__ qout, short* __restrict__ kout,
    short* __restrict__ vout, float* __restrict__ fout) {
  __shared__ short As[128 * 32];
  __shared__ short Bs[128 * 32];
  const int tid = threadIdx.x;
  const int l = tid & 63, w = tid >> 6;
  const int lr = l & 15, g = l >> 4;
  const int bm = blockIdx.y * 128, bn = blockIdx.x * 128;
  const int wm = w >> 1, wn = w & 1;

  f32x4 acc[4][4];
  const f32x4 z4 = {0.f, 0.f, 0.f, 0.f};
#pragma unroll
  for (int m = 0; m < 4; ++m)
#pragma unroll
    for (int n = 0; n < 4; ++n) acc[m][n] = z4;

  for (int k0 = 0; k0 < K; k0 += 32) {
    __syncthreads();
    // stage: row = w*16 + lr (+64*it), kc = g ; swizzle keeps writes+reads ~2-way
#pragma unroll
    for (int it = 0; it < 2; ++it) {
      int row = w * 16 + lr + 64 * it;
      s16x8 va = *(const s16x8*)(A + (size_t)(bm + row) * K + k0 + g * 8);
      s16x8 vb = *(const s16x8*)(Bt + (size_t)(bn + row) * K + k0 + g * 8);
      int byte = (row * 64 + g * 16) ^ ((((unsigned)row >> 1) & 7) << 4);
      *(s16x8*)((char*)As + byte) = va;
      *(s16x8*)((char*)Bs + byte) = vb;
    }
    __syncthreads();
    s16x8 af[4], bfr[4];
#pragma unroll
    for (int m = 0; m < 4; ++m) {
      int row = wm * 64 + m * 16 + lr;
      int byte = (row * 64 + g * 16) ^ ((((unsigned)row >> 1) & 7) << 4);
      af[m] = *(const s16x8*)((char*)As + byte);
    }
#pragma unroll
    for (int n = 0; n < 4; ++n) {
      int row = wn * 64 + n * 16 + lr;
      int byte = (row * 64 + g * 16) ^ ((((unsigned)row >> 1) & 7) << 4);
      bfr[n] = *(const s16x8*)((char*)Bs + byte);
    }
#pragma unroll
    for (int m = 0; m < 4; ++m)
#pragma unroll
      for (int n = 0; n < 4; ++n)
        acc[m][n] = __builtin_amdgcn_mfma_f32_16x16x32_bf16(af[m], bfr[n],
                                                            acc[m][n], 0, 0, 0);
  }

  // epilogue: C row (within 16-tile) = g*4+i, col = lr
#pragma unroll
  for (int m = 0; m < 4; ++m) {
    int rbase = bm + wm * 64 + m * 16 + g * 4;
#pragma unroll
    for (int n = 0; n < 4; ++n) {
      int col = bn + wn * 64 + n * 16 + lr;
      float bv = bias[col];
      if (mode == 0) {
        int which = (col >= 1536) ? 2 : (col >= 768 ? 1 : 0);
        int rem = col - which * 768;
        int h = rem >> 6, d = rem & 63;
#pragma unroll
        for (int i = 0; i < 4; ++i) {
          int r = rbase + i;
          int b = r >> 11, s = r & 2047;
          short o = f2b(acc[m][n][i] + bv);
          size_t bh = (size_t)b * HDIM + h;
          if (which == 0)      qout[(bh * SDIM + s) * DDIM + d] = o;
          else if (which == 1) kout[(bh * SDIM + s) * DDIM + d] = o;
          else                 vout[(bh * DDIM + d) * SDIM + s] = o;  // V transposed
        }
      } else {
#pragma unroll
        for (int i = 0; i < 4; ++i)
          fout[(size_t)(rbase + i) * N + col] = acc[m][n][i] + bv;
      }
    }
  }
}

// ---------------- flash attention, bf16 MFMA ----------------
// qb,kb: [BH][S][D] bf16 ; vb: [BH][D][S] bf16 ; ao: [B*S][E] bf16
__global__ __launch_bounds__(256) void attn_mfma(
    const short* __restrict__ qb, const short* __restrict__ kb,
    const short* __restrict__ vb, short* __restrict__ ao) {
  __shared__ short Ks[64 * 64];
  __shared__ short Vts[64 * 64];
  __shared__ float Ss[4][16 * 64];
  const int tid = threadIdx.x;
  const int l = tid & 63, w = tid >> 6;
  const int lr = l & 15, g = l >> 4;
  const int qt = gridDim.x - 1 - blockIdx.x;  // long blocks first
  const int bh = blockIdx.y;
  const size_t base = (size_t)bh * SDIM * DDIM;
  const int q0 = qt * 64 + w * 16;

  // Q A-fragments (2 k-steps over D=64), straight from global
  s16x8 qa[2];
#pragma unroll
  for (int s = 0; s < 2; ++s)
    qa[s] = *(const s16x8*)(qb + base + (size_t)(q0 + lr) * DDIM + s * 32 + g * 8);

  const f32x4 z4 = {0.f, 0.f, 0.f, 0.f};
  f32x4 acco[4];
#pragma unroll
  for (int nd = 0; nd < 4; ++nd) acco[nd] = z4;
  float mrun[4], lrun[4];
#pragma unroll
  for (int i = 0; i < 4; ++i) { mrun[i] = -1e30f; lrun[i] = 0.f; }

  char* ssb = (char*)Ss[w];

  for (int kt = 0; kt <= qt; ++kt) {
    __syncthreads();
    // stage K tile [key][d] and Vt tile [d][key], XOR-swizzled rows
#pragma unroll
    for (int it = 0; it < 2; ++it) {
      int row = w * 16 + lr;          // 0..63 across 4 waves
      int c8 = g + 4 * it;            // 8 x 16B chunks per 128B row
      s16x8 kv = *(const s16x8*)(kb + base + (size_t)(kt * 64 + row) * DDIM + c8 * 8);
      s16x8 vv = *(const s16x8*)(vb + base + (size_t)row * SDIM + kt * 64 + c8 * 8);
      int byte = (row * 128 + c8 * 16) ^ ((row & 7) << 4);
      *(s16x8*)((char*)Ks + byte) = kv;
      *(s16x8*)((char*)Vts + byte) = vv;
    }
    __syncthreads();

    // S = Q K^T  (4 col-tiles x 2 k-steps)
    f32x4 sacc[4];
#pragma unroll
    for (int nt = 0; nt < 4; ++nt) sacc[nt] = z4;
#pragma unroll
    for (int s = 0; s < 2; ++s)
#pragma unroll
      for (int nt = 0; nt < 4; ++nt) {
        int key = nt * 16 + lr;
        int byte = (key * 128 + s * 64 + g * 16) ^ ((key & 7) << 4);
        s16x8 kf = *(const s16x8*)((char*)Ks + byte);
        sacc[nt] = __builtin_amdgcn_mfma_f32_16x16x32_bf16(qa[s], kf, sacc[nt], 0, 0, 0);
      }

    // scale + causal mask + row max (rows live in (g,reg i); cols across 16 lanes)
    float rmax[4];
#pragma unroll
    for (int i = 0; i < 4; ++i) rmax[i] = -1e30f;
#pragma unroll
    for (int nt = 0; nt < 4; ++nt)
#pragma unroll
      for (int i = 0; i < 4; ++i) {
        float sv = sacc[nt][i] * 0.125f;
        int qrow = q0 + g * 4 + i;
        int kcol = kt * 64 + nt * 16 + lr;
        sv = (kcol > qrow) ? -1e30f : sv;
        sacc[nt][i] = sv;
        rmax[i] = fmaxf(rmax[i], sv);
      }
#pragma unroll
    for (int off = 1; off < 16; off <<= 1)
#pragma unroll
      for (int i = 0; i < 4; ++i)
        rmax[i] = fmaxf(rmax[i], __shfl_xor(rmax[i], off, 64));

    float alpha[4];
#pragma unroll
    for (int i = 0; i < 4; ++i) {
      float newm = fmaxf(mrun[i], rmax[i]);
      alpha[i] = __expf(mrun[i] - newm);
      mrun[i] = newm;
      lrun[i] *= alpha[i];
    }

    // P = exp(S - m): write to per-wave swizzled f32 strip, accumulate row sums
    float rsum[4] = {0.f, 0.f, 0.f, 0.f};
#pragma unroll
    for (int nt = 0; nt < 4; ++nt)
#pragma unroll
      for (int i = 0; i < 4; ++i) {
        float p = __expf(sacc[nt][i] - mrun[i]);
        rsum[i] += p;
        int row = g * 4 + i;
        int wbyte = (row * 256 + (nt * 16 + lr) * 4) ^ ((row & 7) << 4);
        *(float*)(ssb + wbyte) = p;
      }
#pragma unroll
    for (int off = 1; off < 16; off <<= 1)
#pragma unroll
      for (int i = 0; i < 4; ++i)
        rsum[i] += __shfl_xor(rsum[i], off, 64);
#pragma unroll
    for (int i = 0; i < 4; ++i) lrun[i] += rsum[i];

    // rescale O (same row layout as S -> lane-local)
#pragma unroll
    for (int nd = 0; nd < 4; ++nd)
#pragma unroll
      for (int i = 0; i < 4; ++i) acco[nd][i] *= alpha[i];

    // PV: P A-frags from Ss (f32 -> bf16), V B-frags from Vts
#pragma unroll
    for (int s = 0; s < 2; ++s) {
      int pbyte = (lr * 256 + s * 128 + g * 32) ^ ((lr & 7) << 4);
      f32x4 p0 = *(const f32x4*)(ssb + pbyte);
      f32x4 p1 = *(const f32x4*)(ssb + (pbyte ^ 16));
      s16x8 pa;
#pragma unroll
      for (int j = 0; j < 4; ++j) pa[j] = f2b(p0[j]);
#pragma unroll
      for (int j = 0; j < 4; ++j) pa[4 + j] = f2b(p1[j]);
#pragma unroll
      for (int nd = 0; nd < 4; ++nd) {
        int drow = nd * 16 + lr;
        int byte = (drow * 128 + s * 64 + g * 16) ^ ((drow & 7) << 4);
        s16x8 vf = *(const s16x8*)((char*)Vts + byte);
        acco[nd] = __builtin_amdgcn_mfma_f32_16x16x32_bf16(pa, vf, acco[nd], 0, 0, 0);
      }
    }
  }

  // normalize + store
  const int b = bh / HDIM, h = bh % HDIM;
#pragma unroll
  for (int i = 0; i < 4; ++i) {
    float inv = 1.0f / lrun[i];
    int r = q0 + g * 4 + i;
    size_t orow = ((size_t)b * SDIM + r) * EDIM + h * DDIM;
#pragma unroll
    for (int nd = 0; nd < 4; ++nd)
      ao[orow + nd * 16 + lr] = f2b(acco[nd][i] * inv);
  }
}

extern "C" void kernel_launch(void* const* d_in, const int* in_sizes, int n_in,
                              void* d_out, int out_size, void* d_ws,
                              size_t ws_size, hipStream_t stream) {
  const float* x = (const float*)d_in[0];
  const float* w_qkv = (const float*)d_in[1];
  const float* b_qkv = (const float*)d_in[2];
  const float* w_proj = (const float*)d_in[3];
  const float* b_proj = (const float*)d_in[4];
  float* out = (float*)d_out;

  char* p = (char*)d_ws;
  short* xb = (short*)p;      p += (size_t)MROWS * EDIM * 2;
  short* wqkvt = (short*)p;   p += (size_t)NQKV * EDIM * 2;
  short* wprojt = (short*)p;  p += (size_t)EDIM * EDIM * 2;
  short* qbuf = (short*)p;    p += (size_t)NBH * SDIM * DDIM * 2;
  short* kbuf = (short*)p;    p += (size_t)NBH * SDIM * DDIM * 2;
  short* vbuf = (short*)p;    p += (size_t)NBH * SDIM * DDIM * 2;
  short* aob = (short*)p;     p += (size_t)MROWS * EDIM * 2;

  dim3 blk(256);
  // x -> bf16
  convert_bf16<<<dim3(2048), blk, 0, stream>>>(x, xb, MROWS * EDIM / 4);
  // weights -> transposed bf16
  transpose_bf16<<<dim3(NQKV / 32, EDIM / 32), blk, 0, stream>>>(w_qkv, wqkvt, EDIM, NQKV);
  transpose_bf16<<<dim3(EDIM / 32, EDIM / 32), blk, 0, stream>>>(w_proj, wprojt, EDIM, EDIM);
  // QKV projection + scatter (v transposed)
  gemm_bf16<<<dim3(NQKV / 128, MROWS / 128), blk, 0, stream>>>(
      xb, wqkvt, b_qkv, MROWS, NQKV, EDIM, 0, qbuf, kbuf, vbuf, nullptr);
  // attention
  attn_mfma<<<dim3(SDIM / 64, NBH), blk, 0, stream>>>(qbuf, kbuf, vbuf, aob);
  // output projection
  gemm_bf16<<<dim3(EDIM / 128, MROWS / 128), blk, 0, stream>>>(
      aob, wprojt, b_proj, MROWS, EDIM, EDIM, 1, nullptr, nullptr, nullptr, out);
}